// Round 1
// baseline (2606.095 us; speedup 1.0000x reference)
//
#include <hip/hip_runtime.h>
#include <math.h>

// Problem constants (fixed by the reference)
constexpr int NN  = 50000;   // nodes
constexpr int NE  = 600000;  // edges
constexpr int D   = 128;     // DIM == HID
constexpr int IND = 392;     // 3*DIM + TEMB

__device__ __forceinline__ float4 ld4(const float* p) { return *reinterpret_cast<const float4*>(p); }
__device__ __forceinline__ void   st4(float* p, float4 v) { *reinterpret_cast<float4*>(p) = v; }

// ---------------------------------------------------------------------------
// GEMM tile core: C[64 rows][128 outs] += X[64][128k] * W[128 outs][128k]^T
// per-thread register tile: 4 rows x 8 outputs. X in LDS (rows padded to 132
// floats: stride 132 -> bank (4*row+k)%32 -> 2-way max on reads = free).
// W rows streamed from global (64KB working set, L1/L2 resident).
// ---------------------------------------------------------------------------
__device__ __forceinline__ void gemm_tile(const float (*X)[132],
                                          const float* __restrict__ W, int ldw,
                                          int r0, int o0, float acc[4][8])
{
#pragma unroll 2
  for (int k = 0; k < 128; k += 4) {
    float4 x[4];
#pragma unroll
    for (int i = 0; i < 4; ++i) x[i] = ld4(&X[r0 + i][k]);
#pragma unroll
    for (int j = 0; j < 8; ++j) {
      float4 w = ld4(&W[(o0 + j) * ldw + k]);
#pragma unroll
      for (int i = 0; i < 4; ++i) {
        acc[i][j] = fmaf(x[i].x, w.x, acc[i][j]);
        acc[i][j] = fmaf(x[i].y, w.y, acc[i][j]);
        acc[i][j] = fmaf(x[i].z, w.z, acc[i][j]);
        acc[i][j] = fmaf(x[i].w, w.w, acc[i][j]);
      }
    }
  }
}

__device__ __forceinline__ void zero_acc(float acc[4][8]) {
#pragma unroll
  for (int i = 0; i < 4; ++i)
#pragma unroll
    for (int j = 0; j < 8; ++j) acc[i][j] = 0.0f;
}

// ---------------------------------------------------------------------------
// K1: per-node precompute.
//   A[n]  = ew1[:,   0:128] . z[n]
//   B[n]  = ew1[:, 128:256] . z[n]
//   M[n]  = mw2 . relu(mw1 . z[n] + mb1) + mb2
// ---------------------------------------------------------------------------
__global__ __launch_bounds__(256) void k_node(
    const float* __restrict__ z, const float* __restrict__ ew1,
    const float* __restrict__ mw1, const float* __restrict__ mb1,
    const float* __restrict__ mw2, const float* __restrict__ mb2,
    float* __restrict__ A, float* __restrict__ B, float* __restrict__ M)
{
  __shared__ float X[64][132];
  const int t  = threadIdx.x;
  const int n0 = blockIdx.x * 64;

  // stage z tile (coalesced: 32 consecutive lanes cover one 512B row)
#pragma unroll
  for (int c = 0; c < 8; ++c) {
    int f = c * 256 + t, r = f >> 5, c4 = f & 31;
    float4 v = make_float4(0.f, 0.f, 0.f, 0.f);
    if (n0 + r < NN) v = ld4(&z[(size_t)(n0 + r) * D + c4 * 4]);
    st4(&X[r][c4 * 4], v);
  }
  __syncthreads();

  const int r0 = (t >> 4) * 4;  // row-group base
  const int o0 = (t & 15) * 8;  // out-group base
  float acc[4][8];

  // ---- A ----
  zero_acc(acc);
  gemm_tile(X, ew1, IND, r0, o0, acc);
#pragma unroll
  for (int i = 0; i < 4; ++i) {
    int n = n0 + r0 + i;
    if (n < NN) {
      st4(&A[(size_t)n * D + o0],     make_float4(acc[i][0], acc[i][1], acc[i][2], acc[i][3]));
      st4(&A[(size_t)n * D + o0 + 4], make_float4(acc[i][4], acc[i][5], acc[i][6], acc[i][7]));
    }
  }

  // ---- B ----
  zero_acc(acc);
  gemm_tile(X, ew1 + 128, IND, r0, o0, acc);
#pragma unroll
  for (int i = 0; i < 4; ++i) {
    int n = n0 + r0 + i;
    if (n < NN) {
      st4(&B[(size_t)n * D + o0],     make_float4(acc[i][0], acc[i][1], acc[i][2], acc[i][3]));
      st4(&B[(size_t)n * D + o0 + 4], make_float4(acc[i][4], acc[i][5], acc[i][6], acc[i][7]));
    }
  }

  // ---- M layer 1: h1 = relu(mw1.z + mb1), swapped through LDS ----
  zero_acc(acc);
  gemm_tile(X, mw1, D, r0, o0, acc);
  __syncthreads();  // everyone done reading z-tile
#pragma unroll
  for (int i = 0; i < 4; ++i)
#pragma unroll
    for (int j = 0; j < 8; ++j)
      X[r0 + i][o0 + j] = fmaxf(acc[i][j] + mb1[o0 + j], 0.0f);
  __syncthreads();

  // ---- M layer 2 ----
  zero_acc(acc);
  gemm_tile(X, mw2, D, r0, o0, acc);
#pragma unroll
  for (int i = 0; i < 4; ++i) {
    int n = n0 + r0 + i;
    if (n < NN) {
      st4(&M[(size_t)n * D + o0],
          make_float4(acc[i][0] + mb2[o0 + 0], acc[i][1] + mb2[o0 + 1],
                      acc[i][2] + mb2[o0 + 2], acc[i][3] + mb2[o0 + 3]));
      st4(&M[(size_t)n * D + o0 + 4],
          make_float4(acc[i][4] + mb2[o0 + 4], acc[i][5] + mb2[o0 + 5],
                      acc[i][6] + mb2[o0 + 6], acc[i][7] + mb2[o0 + 7]));
    }
  }
}

// ---------------------------------------------------------------------------
// K2: per-edge pass. 64 edges/block.
//   hc = Wc . |z[src]-z[dst]|   (Wc = ew1[:,256:384], the only true per-edge GEMM)
//   h  = relu(hc + A[src] + B[dst] + tvec[type] + eb1)
//   w  = sigmoid(h . ew2 + eb2);  wexp = exp(w);  sumw[src] += wexp (atomic)
// (max-subtraction dropped: w in (0,1) so exp(w) is stable; alpha identical
//  to reference up to ~1e-12 relative.)
// ---------------------------------------------------------------------------
__global__ __launch_bounds__(256) void k_edge(
    const float* __restrict__ z, const int* __restrict__ ei,
    const int* __restrict__ etype, const float* __restrict__ type_emb,
    const float* __restrict__ ew1, const float* __restrict__ eb1,
    const float* __restrict__ ew2, const float* __restrict__ eb2,
    const float* __restrict__ A, const float* __restrict__ B,
    float* __restrict__ wexp, float* __restrict__ sumw)
{
  __shared__ float X[64][132];
  __shared__ float tv[2][128];
  __shared__ int   se[64], de[64], tye[64];
  __shared__ float part[64][17];  // +1 pad to spread banks on the reduce

  const int t  = threadIdx.x;
  const int e0 = blockIdx.x * 64;

  // type-embedding contribution: tv[ty][o] = sum_j ew1[o][384+j]*type_emb[ty][j]
  {
    int o = t & 127, ty = t >> 7;
    float s = 0.f;
#pragma unroll
    for (int j = 0; j < 8; ++j) s += ew1[o * IND + 384 + j] * type_emb[ty * 8 + j];
    tv[ty][o] = s;
  }
  if (t < 64) {
    se[t] = ei[e0 + t];
    de[t] = ei[NE + e0 + t];
    tye[t] = etype[e0 + t];
  }
  __syncthreads();

  // stage |z[src]-z[dst]| (32 lanes cover one 512B row -> coalesced gather)
#pragma unroll
  for (int c = 0; c < 8; ++c) {
    int f = c * 256 + t, r = f >> 5, c4 = f & 31;
    float4 a = ld4(&z[(size_t)se[r] * D + c4 * 4]);
    float4 b = ld4(&z[(size_t)de[r] * D + c4 * 4]);
    st4(&X[r][c4 * 4], make_float4(fabsf(a.x - b.x), fabsf(a.y - b.y),
                                   fabsf(a.z - b.z), fabsf(a.w - b.w)));
  }
  __syncthreads();

  const int r0 = (t >> 4) * 4;
  const int o0 = (t & 15) * 8;
  float acc[4][8];
  zero_acc(acc);
  gemm_tile(X, ew1 + 256, IND, r0, o0, acc);  // Wc term

  // epilogue: finish h for my (4 edges x 8 outs), partial dot with ew2
#pragma unroll
  for (int i = 0; i < 4; ++i) {
    int el = r0 + i;
    int s = se[el], dd = de[el], ty = tye[el];
    float4 a0 = ld4(&A[(size_t)s * D + o0]),  a1 = ld4(&A[(size_t)s * D + o0 + 4]);
    float4 b0 = ld4(&B[(size_t)dd * D + o0]), b1 = ld4(&B[(size_t)dd * D + o0 + 4]);
    float4 t0 = ld4(&tv[ty][o0]),             t1 = ld4(&tv[ty][o0 + 4]);
    float4 c0 = ld4(&eb1[o0]),                c1 = ld4(&eb1[o0 + 4]);
    float4 w0 = ld4(&ew2[o0]),                w1 = ld4(&ew2[o0 + 4]);
    float p = 0.f, h;
    h = acc[i][0] + a0.x + b0.x + t0.x + c0.x; p += fmaxf(h, 0.f) * w0.x;
    h = acc[i][1] + a0.y + b0.y + t0.y + c0.y; p += fmaxf(h, 0.f) * w0.y;
    h = acc[i][2] + a0.z + b0.z + t0.z + c0.z; p += fmaxf(h, 0.f) * w0.z;
    h = acc[i][3] + a0.w + b0.w + t0.w + c0.w; p += fmaxf(h, 0.f) * w0.w;
    h = acc[i][4] + a1.x + b1.x + t1.x + c1.x; p += fmaxf(h, 0.f) * w1.x;
    h = acc[i][5] + a1.y + b1.y + t1.y + c1.y; p += fmaxf(h, 0.f) * w1.y;
    h = acc[i][6] + a1.z + b1.z + t1.z + c1.z; p += fmaxf(h, 0.f) * w1.z;
    h = acc[i][7] + a1.w + b1.w + t1.w + c1.w; p += fmaxf(h, 0.f) * w1.w;
    part[el][t & 15] = p;
  }
  __syncthreads();

  if (t < 64) {
    float s = 0.f;
#pragma unroll
    for (int g = 0; g < 16; ++g) s += part[t][g];
    s += eb2[0];
    float w  = 1.0f / (1.0f + expf(-s));  // sigmoid
    float we = expf(w);
    wexp[e0 + t] = we;
    atomicAdd(&sumw[se[t]], we);
  }
}

// ---------------------------------------------------------------------------
// K3: scatter. alpha = wexp/(sum[src]+1e-12); agg[src] += alpha*M[dst].
// 32 lanes per edge (4 floats each).
// ---------------------------------------------------------------------------
__global__ __launch_bounds__(256) void k_scatter(
    const int* __restrict__ ei, const float* __restrict__ wexp,
    const float* __restrict__ sumw, const float* __restrict__ M,
    float* __restrict__ agg, float* __restrict__ alpha_out)
{
  const int t = threadIdx.x;
  const int e = blockIdx.x * 8 + (t >> 5);
  const int l = t & 31;
  const int s = ei[e], dd = ei[NE + e];
  const float alpha = wexp[e] / (sumw[s] + 1e-12f);
  if (l == 0) alpha_out[e] = alpha;
  float4 m = ld4(&M[(size_t)dd * D + l * 4]);
  float* ap = &agg[(size_t)s * D + l * 4];
  atomicAdd(ap + 0, alpha * m.x);
  atomicAdd(ap + 1, alpha * m.y);
  atomicAdd(ap + 2, alpha * m.z);
  atomicAdd(ap + 3, alpha * m.w);
}

// ---------------------------------------------------------------------------
// K4: residual + LayerNorm. One wave per row.
// ---------------------------------------------------------------------------
__global__ __launch_bounds__(256) void k_ln(
    const float* __restrict__ z, const float* __restrict__ agg,
    const float* __restrict__ gamma, const float* __restrict__ beta,
    float* __restrict__ out)
{
  const int t = threadIdx.x;
  const int n = blockIdx.x * 4 + (t >> 6);
  const int l = t & 63;
  if (n >= NN) return;
  float2 xz = *reinterpret_cast<const float2*>(&z[(size_t)n * D + l * 2]);
  float2 xa = *reinterpret_cast<const float2*>(&agg[(size_t)n * D + l * 2]);
  float x0 = xz.x + xa.x, x1 = xz.y + xa.y;
  float s = x0 + x1;
#pragma unroll
  for (int off = 32; off; off >>= 1) s += __shfl_xor(s, off);
  const float mu = s * (1.0f / 128.0f);
  float d0 = x0 - mu, d1 = x1 - mu;
  float q = d0 * d0 + d1 * d1;
#pragma unroll
  for (int off = 32; off; off >>= 1) q += __shfl_xor(q, off);
  const float rstd = rsqrtf(q * (1.0f / 128.0f) + 1e-5f);
  float2 g = *reinterpret_cast<const float2*>(&gamma[l * 2]);
  float2 b = *reinterpret_cast<const float2*>(&beta[l * 2]);
  float2 o = make_float2(d0 * rstd * g.x + b.x, d1 * rstd * g.y + b.y);
  *reinterpret_cast<float2*>(&out[(size_t)n * D + l * 2]) = o;
}

// ---------------------------------------------------------------------------
extern "C" void kernel_launch(void* const* d_in, const int* in_sizes, int n_in,
                              void* d_out, int out_size, void* d_ws, size_t ws_size,
                              hipStream_t stream)
{
  const float* z        = (const float*)d_in[0];
  const int*   ei       = (const int*)d_in[1];   // [2,E]: src row, then dst row
  const int*   etype    = (const int*)d_in[2];
  const float* type_emb = (const float*)d_in[3];
  const float* ew1      = (const float*)d_in[4];
  const float* eb1      = (const float*)d_in[5];
  const float* ew2      = (const float*)d_in[6];
  const float* eb2      = (const float*)d_in[7];
  const float* mw1      = (const float*)d_in[8];
  const float* mb1      = (const float*)d_in[9];
  const float* mw2      = (const float*)d_in[10];
  const float* mb2      = (const float*)d_in[11];
  const float* gamma    = (const float*)d_in[12];
  const float* beta     = (const float*)d_in[13];

  // workspace layout (floats): A | B | M | wexp | agg | sumw  (~105 MB)
  float* ws   = (float*)d_ws;
  float* A    = ws;
  float* B    = ws + 6400000;
  float* M    = ws + 12800000;
  float* wexp = ws + 19200000;
  float* agg  = ws + 19800000;
  float* sumw = ws + 26200000;

  float* out       = (float*)d_out;
  float* alpha_out = out + (size_t)NN * D;

  // zero the accumulation buffers (agg + sumw are contiguous)
  hipMemsetAsync(agg, 0, (size_t)(6400000 + 50000) * sizeof(float), stream);

  k_node<<<(NN + 63) / 64, 256, 0, stream>>>(z, ew1, mw1, mb1, mw2, mb2, A, B, M);
  k_edge<<<NE / 64, 256, 0, stream>>>(z, ei, etype, type_emb, ew1, eb1, ew2, eb2,
                                      A, B, wexp, sumw);
  k_scatter<<<NE / 8, 256, 0, stream>>>(ei, wexp, sumw, M, agg, alpha_out);
  k_ln<<<NN / 4, 256, 0, stream>>>(z, agg, gamma, beta, out);
}